// Round 13
// baseline (39.300 us; speedup 1.0000x reference)
//
#include <hip/hip_runtime.h>
#include <hip/hip_fp16.h>

#define NCELL 512
#define EPSF  1e-8f
#define FSCD  0.08838834764831845    // 128**-0.5 (exact double of python repr)

// ---------------- lane-permute primitives (all within 16-lane DPP rows) -----
template<int CTRL>
__device__ __forceinline__ int idpp(int x){
  return __builtin_amdgcn_update_dpp(x, x, CTRL, 0xF, 0xF, false);
}
template<int CTRL>
__device__ __forceinline__ float fdpp(float x){
  return __int_as_float(idpp<CTRL>(__float_as_int(x)));
}
// f32 lane-xor within 16-lane rows
__device__ __forceinline__ float xorl1(float v){ return fdpp<0xB1>(v); }              // quad_perm [1,0,3,2]
__device__ __forceinline__ float xorl2(float v){ return fdpp<0x4E>(v); }              // quad_perm [2,3,0,1]
__device__ __forceinline__ float xorl4(float v){ return fdpp<0x1B>(fdpp<0x141>(v)); } // half_mirror(x^7) o quad[3,2,1,0](x^3)
__device__ __forceinline__ float xorl8(float v){ return fdpp<0x128>(v); }             // row_ror:8 == x^8 in 16

// f32 butterfly reductions over a 16-lane row; bitwise lane-uniform.
__device__ __forceinline__ float redsum16f(float v){
  v += xorl1(v); v += xorl2(v); v += xorl4(v); v += xorl8(v); return v;
}
__device__ __forceinline__ float redmax16f(float v){
  v = fmaxf(v,xorl1(v)); v = fmaxf(v,xorl2(v));
  v = fmaxf(v,xorl4(v)); v = fmaxf(v,xorl8(v)); return v;
}

// ------- 128-pt FWHT, f32, 8 elems/lane (e = 8*li + j), 16 lanes/row --------
__device__ __forceinline__ void fwht128f_8(float r[8], float sA, float sB,
                                           float sC, float sD){
  float t;
  t=r[0]; r[0]=t+r[1]; r[1]=t-r[1];  t=r[2]; r[2]=t+r[3]; r[3]=t-r[3];
  t=r[4]; r[4]=t+r[5]; r[5]=t-r[5];  t=r[6]; r[6]=t+r[7]; r[7]=t-r[7];
  t=r[0]; r[0]=t+r[2]; r[2]=t-r[2];  t=r[1]; r[1]=t+r[3]; r[3]=t-r[3];
  t=r[4]; r[4]=t+r[6]; r[6]=t-r[6];  t=r[5]; r[5]=t+r[7]; r[7]=t-r[7];
  t=r[0]; r[0]=t+r[4]; r[4]=t-r[4];  t=r[1]; r[1]=t+r[5]; r[5]=t-r[5];
  t=r[2]; r[2]=t+r[6]; r[6]=t-r[6];  t=r[3]; r[3]=t+r[7]; r[7]=t-r[7];
  #pragma unroll
  for (int j=0;j<8;++j){ float o=xorl1(r[j]); r[j]=fmaf(sA, r[j], o); }
  #pragma unroll
  for (int j=0;j<8;++j){ float o=xorl2(r[j]); r[j]=fmaf(sB, r[j], o); }
  #pragma unroll
  for (int j=0;j<8;++j){ float o=xorl4(r[j]); r[j]=fmaf(sC, r[j], o); }
  #pragma unroll
  for (int j=0;j<8;++j){ float o=xorl8(r[j]); r[j]=fmaf(sD, r[j], o); }
}

__global__ __launch_bounds__(256) void tq_kernel(
    const float* __restrict__ x, const float* __restrict__ signs,
    const float* __restrict__ bnd, const float* __restrict__ ctr,
    float* __restrict__ out, int nquads)
{
  // One-gather searchsorted LUT (R8 reach construction), 8-byte entries:
  //   {f32 b*, u32 = f16(C_hi)<<16 | f16(C_lo)}  (see R12 error budget)
  __shared__ uint2  lutE[NCELL];   // 4 KB
  __shared__ double Bd[256];       // 2 KB (255 boundaries + +inf sentinel)
  const int tid = threadIdx.x;
  if (tid < 255)  Bd[tid] = (double)bnd[tid];
  if (tid == 255) Bd[255] = __builtin_inf();
  __syncthreads();

  const double lo    = Bd[0] - 0.01;
  const double cw    = (Bd[254] + 0.01 - lo) * (1.0 / NCELL);
  const double scale = 1.0 / cw;
  const double nls   = -lo * scale;
  const double epsg  = cw * 1e-3;       // >> f32 addressing slop (~2e-4 cells)

  for (int c = tid; c < NCELL; c += 256) {
    double wl = (c == 0)         ? -__builtin_inf() : fma((double)c,     cw, lo) - epsg;
    double wr = (c == NCELL - 1) ?  __builtin_inf() : fma((double)(c+1), cw, lo) + epsg;
    int n = 0;
    #pragma unroll
    for (int s = 128; s; s >>= 1) n += (Bd[n + s - 1] < wl) ? s : 0;  // n = #{B < wl}
    double b  = Bd[n];                  // +inf sentinel at n==255
    bool  has = (b < wr);               // unique boundary in reach, if any
    float c_lo = ctr[n];
    float c_hi = ctr[has ? (n + 1) : n];          // has => n<=254
    uint2 e;
    e.x = __float_as_uint(has ? (float)b : __builtin_inff());
    e.y = ((unsigned)__half_as_ushort(__float2half_rn(c_hi)) << 16)
        |  (unsigned)__half_as_ushort(__float2half_rn(c_lo));
    lutE[c] = e;
  }
  __syncthreads();

  const int l   = tid & 63;
  const int li  = l & 15;         // lane within 16-lane row
  const int rw  = (l >> 4) & 3;   // row within wave (4 rows/wave)
  const int wid = tid >> 6;
  const float sAf = (l & 1) ? -1.f : 1.f;
  const float sBf = (l & 2) ? -1.f : 1.f;
  const float sCf = (l & 4) ? -1.f : 1.f;
  const float sDf = (l & 8) ? -1.f : 1.f;
  const float inv_maxcf = (float)(1.0 / (double)ctr[255]);
  const float scf   = (float)scale;
  const float nlsf  = (float)nls;
  const float icmax = (float)(NCELL - 1);
  const float fscf  = (float)FSCD;

  const float4 sga = *reinterpret_cast<const float4*>(signs + 8 * li);
  const float4 sgb = *reinterpret_cast<const float4*>(signs + 8 * li + 4);

  auto qcent = [&](float vf) -> float {
    float cf = fmaf(vf, scf, nlsf);
    cf = fminf(fmaxf(cf, 0.0f), icmax);
    int ic = (int)cf;
    uint2 e = lutE[ic];
    unsigned h = (__uint_as_float(e.x) < vf) ? (e.y >> 16) : (e.y & 0xFFFFu);
    return __half2float(__ushort_as_half((unsigned short)h));
  };

  const int stride   = gridDim.x * 4;
  const int base_off = rw * 128 + 8 * li;

  // 2-way iteration interleave: per loop, two INDEPENDENT quads (t, t+stride)
  // give each lane two dependency chains -> fills latency bubbles.
  for (int t = blockIdx.x * 4 + wid; t < nquads; t += 2 * stride) {
    const int  tB   = t + stride;
    const bool hasB = (tB < nquads);
    const int  tBc  = hasB ? tB : t;      // clamped: valid addr, store masked

    const float* pA = x + 4 * t   * 128 + base_off;
    const float* pB = x + 4 * tBc * 128 + base_off;
    const float4 a0 = *reinterpret_cast<const float4*>(pA);
    const float4 a1 = *reinterpret_cast<const float4*>(pA + 4);
    const float4 b0 = *reinterpret_cast<const float4*>(pB);
    const float4 b1 = *reinterpret_cast<const float4*>(pB + 4);

    float rA[8], rB[8];
    rA[0]=a0.x*sga.x; rA[1]=a0.y*sga.y; rA[2]=a0.z*sga.z; rA[3]=a0.w*sga.w;
    rA[4]=a1.x*sgb.x; rA[5]=a1.y*sgb.y; rA[6]=a1.z*sgb.z; rA[7]=a1.w*sgb.w;
    rB[0]=b0.x*sga.x; rB[1]=b0.y*sga.y; rB[2]=b0.z*sga.z; rB[3]=b0.w*sga.w;
    rB[4]=b1.x*sgb.x; rB[5]=b1.y*sgb.y; rB[6]=b1.z*sgb.z; rB[7]=b1.w*sgb.w;

    fwht128f_8(rA, sAf, sBf, sCf, sDf);
    fwht128f_8(rB, sAf, sBf, sCf, sDf);

    // fused stats (Parseval norm from rotated domain)
    float ssA=rA[0]*rA[0], mxA=fabsf(rA[0]), asA=mxA;
    float ssB=rB[0]*rB[0], mxB=fabsf(rB[0]), asB=mxB;
    #pragma unroll
    for (int j = 1; j < 8; ++j) {
      ssA = fmaf(rA[j], rA[j], ssA);
      float aj = fabsf(rA[j]); mxA = fmaxf(mxA, aj); asA += aj;
      ssB = fmaf(rB[j], rB[j], ssB);
      float bj = fabsf(rB[j]); mxB = fmaxf(mxB, bj); asB += bj;
    }
    float nfA = __builtin_amdgcn_sqrtf(redsum16f(ssA)) * fscf + EPSF;
    float nfB = __builtin_amdgcn_sqrtf(redsum16f(ssB)) * fscf + EPSF;
    float kfA = fscf * __builtin_amdgcn_rcpf(nfA);
    float kfB = fscf * __builtin_amdgcn_rcpf(nfB);

    float xmaxA  = redmax16f(mxA) * kfA;
    float xmaxB  = redmax16f(mxB) * kfB;
    float xmeanA = fmaf(redsum16f(asA) * 0.0078125f, kfA, EPSF);
    float xmeanB = fmaf(redsum16f(asB) * 0.0078125f, kfB, EPSF);
    bool  spkA = xmaxA > 5.0f * xmeanA;
    bool  spkB = xmaxB > 5.0f * xmeanB;
    float rmsA = xmaxA * inv_maxcf;
    float rmsB = xmaxB * inv_maxcf;

    // pass 1
    float kd1A = kfA * __builtin_amdgcn_rcpf(rmsA + EPSF);
    float kd1B = kfB * __builtin_amdgcn_rcpf(rmsB + EPSF);
    float c1A[8], c1B[8];
    #pragma unroll
    for (int j = 0; j < 8; ++j) { c1A[j] = qcent(rA[j] * kd1A);
                                  c1B[j] = qcent(rB[j] * kd1B); }

    // gamma refine
    float numA=0.f, denA=0.f, numB=0.f, denB=0.f;
    #pragma unroll
    for (int j = 0; j < 8; ++j) {
      numA = fmaf(rA[j], c1A[j], numA);  denA = fmaf(c1A[j], c1A[j], denA);
      numB = fmaf(rB[j], c1B[j], numB);  denB = fmaf(c1B[j], c1B[j], denB);
    }
    float g1A = redsum16f(numA) * kfA * __builtin_amdgcn_rcpf(redsum16f(denA) + EPSF);
    float g1B = redsum16f(numB) * kfB * __builtin_amdgcn_rcpf(redsum16f(denB) + EPSF);

    // pass 2
    float kd2A = kfA * __builtin_amdgcn_rcpf(g1A + EPSF);
    float kd2B = kfB * __builtin_amdgcn_rcpf(g1B + EPSF);
    float c2A[8], c2B[8];
    #pragma unroll
    for (int j = 0; j < 8; ++j) { c2A[j] = qcent(rA[j] * kd2A);
                                  c2B[j] = qcent(rB[j] * kd2B); }

    // reconstruct; fold gamma*FSC*norms into one pre-FWHT scalar (linearity)
    float g2A = (spkA ? rmsA : g1A) * fscf * nfA;
    float g2B = (spkB ? rmsB : g1B) * fscf * nfB;
    float yA[8], yB[8];
    #pragma unroll
    for (int j = 0; j < 8; ++j) { yA[j] = (spkA ? c1A[j] : c2A[j]) * g2A;
                                  yB[j] = (spkB ? c1B[j] : c2B[j]) * g2B; }
    fwht128f_8(yA, sAf, sBf, sCf, sDf);
    fwht128f_8(yB, sAf, sBf, sCf, sDf);

    float* oA = out + 4 * t * 128 + base_off;
    float4 oa, ob;
    oa.x=yA[0]*sga.x; oa.y=yA[1]*sga.y; oa.z=yA[2]*sga.z; oa.w=yA[3]*sga.w;
    ob.x=yA[4]*sgb.x; ob.y=yA[5]*sgb.y; ob.z=yA[6]*sgb.z; ob.w=yA[7]*sgb.w;
    *reinterpret_cast<float4*>(oA)     = oa;
    *reinterpret_cast<float4*>(oA + 4) = ob;
    if (hasB) {
      float* oB = out + 4 * tB * 128 + base_off;
      float4 pa, pb;
      pa.x=yB[0]*sga.x; pa.y=yB[1]*sga.y; pa.z=yB[2]*sga.z; pa.w=yB[3]*sga.w;
      pb.x=yB[4]*sgb.x; pb.y=yB[5]*sgb.y; pb.z=yB[6]*sgb.z; pb.w=yB[7]*sgb.w;
      *reinterpret_cast<float4*>(oB)     = pa;
      *reinterpret_cast<float4*>(oB + 4) = pb;
    }
  }
}

extern "C" void kernel_launch(void* const* d_in, const int* in_sizes, int n_in,
                              void* d_out, int out_size, void* d_ws, size_t ws_size,
                              hipStream_t stream) {
  const float* x     = (const float*)d_in[0];
  const float* signs = (const float*)d_in[1];
  // d_in[2] = wht (unused: Sylvester Hadamard applied as in-register FWHT)
  const float* bnd   = (const float*)d_in[3];
  const float* ctr   = (const float*)d_in[4];
  float* out = (float*)d_out;

  int nrows  = out_size / 128;
  int nquads = nrows / 4;                    // 4 rows per wave
  int blocks = (nquads + 3) / 4;             // 4 waves per block
  if (blocks > 2048) blocks = 2048;
  hipLaunchKernelGGL(tq_kernel, dim3(blocks), dim3(256), 0, stream,
                     x, signs, bnd, ctr, out, nquads);
}

// Round 14
// 39.063 us; speedup vs baseline: 1.0061x; 1.0061x over previous
//
#include <hip/hip_runtime.h>
#include <hip/hip_fp16.h>

#define NCELL 512
#define EPSF  1e-8f
#define FSCD  0.08838834764831845    // 128**-0.5 (exact double of python repr)

typedef float f32x2 __attribute__((ext_vector_type(2)));

// ---------------- lane-permute primitives (all within 16-lane DPP rows) -----
template<int CTRL>
__device__ __forceinline__ int idpp(int x){
  return __builtin_amdgcn_update_dpp(x, x, CTRL, 0xF, 0xF, false);
}
template<int CTRL>
__device__ __forceinline__ float fdpp(float x){
  return __int_as_float(idpp<CTRL>(__float_as_int(x)));
}
// f32 lane-xor within 16-lane rows
__device__ __forceinline__ float xorl1(float v){ return fdpp<0xB1>(v); }              // quad_perm [1,0,3,2]
__device__ __forceinline__ float xorl2(float v){ return fdpp<0x4E>(v); }              // quad_perm [2,3,0,1]
__device__ __forceinline__ float xorl4(float v){ return fdpp<0x1B>(fdpp<0x141>(v)); } // half_mirror(x^7) o quad[3,2,1,0](x^3)
__device__ __forceinline__ float xorl8(float v){ return fdpp<0x128>(v); }             // row_ror:8 == x^8 in 16
// packed variants: DPP each 32-bit half, keep pair adjacency for pk ops
template<int CTRL>
__device__ __forceinline__ f32x2 vdpp(f32x2 v){
  f32x2 r; r.x = fdpp<CTRL>(v.x); r.y = fdpp<CTRL>(v.y); return r;
}
__device__ __forceinline__ f32x2 vxor1(f32x2 v){ return vdpp<0xB1>(v); }
__device__ __forceinline__ f32x2 vxor2(f32x2 v){ return vdpp<0x4E>(v); }
__device__ __forceinline__ f32x2 vxor4(f32x2 v){ return vdpp<0x1B>(vdpp<0x141>(v)); }
__device__ __forceinline__ f32x2 vxor8(f32x2 v){ return vdpp<0x128>(v); }

// f32 butterfly reductions over a 16-lane row; bitwise lane-uniform.
__device__ __forceinline__ float redsum16f(float v){
  v += xorl1(v); v += xorl2(v); v += xorl4(v); v += xorl8(v); return v;
}
__device__ __forceinline__ float redmax16f(float v){
  v = fmaxf(v,xorl1(v)); v = fmaxf(v,xorl2(v));
  v = fmaxf(v,xorl4(v)); v = fmaxf(v,xorl8(v)); return v;
}

// ------- 128-pt FWHT, packed f32x2, 8 elems/lane (4 pairs), 16 lanes/row ----
// e = 8*li + j; pairs (j=0,1)(2,3)(4,5)(6,7). Strides 1,2,4 in-register
// (2,4 fully packed); strides 8..64 via lane-xor DPP + packed FMA.
__device__ __forceinline__ void fwht128v(f32x2 v[4], f32x2 sA, f32x2 sB,
                                         f32x2 sC, f32x2 sD){
  // stride 1: within pair (a,b) -> (a+b, a-b)
  #pragma unroll
  for (int i = 0; i < 4; ++i) {
    float a = v[i].x, b = v[i].y;
    v[i].x = a + b; v[i].y = a - b;
  }
  // stride 2: pair i with i+1 (packed)
  { f32x2 t = v[0]; v[0] = t + v[1]; v[1] = t - v[1];
    t = v[2]; v[2] = t + v[3]; v[3] = t - v[3]; }
  // stride 4: pair i with i+2 (packed)
  { f32x2 t = v[0]; v[0] = t + v[2]; v[2] = t - v[2];
    t = v[1]; v[1] = t + v[3]; v[3] = t - v[3]; }
  // cross-lane stages: o = dpp(v); v = s*v + o  (packed fma)
  #pragma unroll
  for (int i = 0; i < 4; ++i) { f32x2 o = vxor1(v[i]); v[i] = __builtin_elementwise_fma(sA, v[i], o); }
  #pragma unroll
  for (int i = 0; i < 4; ++i) { f32x2 o = vxor2(v[i]); v[i] = __builtin_elementwise_fma(sB, v[i], o); }
  #pragma unroll
  for (int i = 0; i < 4; ++i) { f32x2 o = vxor4(v[i]); v[i] = __builtin_elementwise_fma(sC, v[i], o); }
  #pragma unroll
  for (int i = 0; i < 4; ++i) { f32x2 o = vxor8(v[i]); v[i] = __builtin_elementwise_fma(sD, v[i], o); }
}

__global__ __launch_bounds__(256) void tq_kernel(
    const float* __restrict__ x, const float* __restrict__ signs,
    const float* __restrict__ bnd, const float* __restrict__ ctr,
    float* __restrict__ out, int nquads)
{
  // One-gather searchsorted LUT (R8 reach construction), 8-byte entries:
  //   {f32 b*, u32 = f16(C_hi)<<16 | f16(C_lo)}  (see R12 error budget)
  __shared__ uint2  lutE[NCELL];   // 4 KB
  __shared__ double Bd[256];       // 2 KB (255 boundaries + +inf sentinel)
  const int tid = threadIdx.x;
  if (tid < 255)  Bd[tid] = (double)bnd[tid];
  if (tid == 255) Bd[255] = __builtin_inf();
  __syncthreads();

  const double lo    = Bd[0] - 0.01;
  const double cw    = (Bd[254] + 0.01 - lo) * (1.0 / NCELL);
  const double scale = 1.0 / cw;
  const double nls   = -lo * scale;
  const double epsg  = cw * 1e-3;       // >> f32 addressing slop (~2e-4 cells)

  for (int c = tid; c < NCELL; c += 256) {
    double wl = (c == 0)         ? -__builtin_inf() : fma((double)c,     cw, lo) - epsg;
    double wr = (c == NCELL - 1) ?  __builtin_inf() : fma((double)(c+1), cw, lo) + epsg;
    int n = 0;
    #pragma unroll
    for (int s = 128; s; s >>= 1) n += (Bd[n + s - 1] < wl) ? s : 0;  // n = #{B < wl}
    double b  = Bd[n];                  // +inf sentinel at n==255
    bool  has = (b < wr);               // unique boundary in reach, if any
    float c_lo = ctr[n];
    float c_hi = ctr[has ? (n + 1) : n];          // has => n<=254
    uint2 e;
    e.x = __float_as_uint(has ? (float)b : __builtin_inff());
    e.y = ((unsigned)__half_as_ushort(__float2half_rn(c_hi)) << 16)
        |  (unsigned)__half_as_ushort(__float2half_rn(c_lo));
    lutE[c] = e;
  }
  __syncthreads();

  const int l   = tid & 63;
  const int li  = l & 15;         // lane within 16-lane row
  const int rw  = (l >> 4) & 3;   // row within wave (4 rows/wave)
  const int wid = tid >> 6;
  const float sAs = (l & 1) ? -1.f : 1.f;
  const float sBs = (l & 2) ? -1.f : 1.f;
  const float sCs = (l & 4) ? -1.f : 1.f;
  const float sDs = (l & 8) ? -1.f : 1.f;
  const f32x2 sAv = { sAs, sAs }, sBv = { sBs, sBs },
              sCv = { sCs, sCs }, sDv = { sDs, sDs };
  const float inv_maxcf = (float)(1.0 / (double)ctr[255]);
  const float scf   = (float)scale;
  const float nlsf  = (float)nls;
  const float icmax = (float)(NCELL - 1);
  const float fscf  = (float)FSCD;

  const float4 sga = *reinterpret_cast<const float4*>(signs + 8 * li);
  const float4 sgb = *reinterpret_cast<const float4*>(signs + 8 * li + 4);
  const f32x2 sg[4] = { { sga.x, sga.y }, { sga.z, sga.w },
                        { sgb.x, sgb.y }, { sgb.z, sgb.w } };

  auto qcent = [&](float vf) -> float {
    float cf = fmaf(vf, scf, nlsf);
    cf = fminf(fmaxf(cf, 0.0f), icmax);
    int ic = (int)cf;
    uint2 e = lutE[ic];
    unsigned h = (__uint_as_float(e.x) < vf) ? (e.y >> 16) : (e.y & 0xFFFFu);
    return __half2float(__ushort_as_half((unsigned short)h));
  };

  const int stride = gridDim.x * 4;
  int t = blockIdx.x * 4 + wid;
  if (t >= nquads) return;

  const int base_off = rw * 128 + 8 * li;
  const float* xp = x + 4 * t * 128 + base_off;
  float4 xa = *reinterpret_cast<const float4*>(xp);
  float4 xb = *reinterpret_cast<const float4*>(xp + 4);

  while (true) {
    const int tn = t + stride;
    const bool more = (tn < nquads);
    const int tpf = more ? tn : t;
    const float* np_ = x + 4 * tpf * 128 + base_off;
    float4 na = *reinterpret_cast<const float4*>(np_);
    float4 nb = *reinterpret_cast<const float4*>(np_ + 4);

    // sign fold (packed), then packed FWHT
    f32x2 r[4];
    r[0] = f32x2{ xa.x, xa.y } * sg[0];
    r[1] = f32x2{ xa.z, xa.w } * sg[1];
    r[2] = f32x2{ xb.x, xb.y } * sg[2];
    r[3] = f32x2{ xb.z, xb.w } * sg[3];

    fwht128v(r, sAv, sBv, sCv, sDv);

    // fused stats (packed accumulate, horizontal finish)
    f32x2 ssv = r[0] * r[0];
    f32x2 abv = __builtin_elementwise_abs(r[0]);
    f32x2 mxv = abv, asv = abv;
    #pragma unroll
    for (int i = 1; i < 4; ++i) {
      ssv = __builtin_elementwise_fma(r[i], r[i], ssv);
      f32x2 a = __builtin_elementwise_abs(r[i]);
      mxv = __builtin_elementwise_max(mxv, a);
      asv = asv + a;
    }
    float ssf = ssv.x + ssv.y;
    float mxf = fmaxf(mxv.x, mxv.y);
    float asf = asv.x + asv.y;

    // norms via Parseval: ||x|| = sqrt(sum r^2)/sqrt(128)
    float nf = __builtin_amdgcn_sqrtf(redsum16f(ssf)) * fscf + EPSF;
    float kf = fscf * __builtin_amdgcn_rcpf(nf);

    float xmaxf  = redmax16f(mxf) * kf;
    float xmeanf = fmaf(redsum16f(asf) * 0.0078125f, kf, EPSF);
    bool  spiky  = xmaxf > 5.0f * xmeanf;
    float rmsf   = xmaxf * inv_maxcf;

    // pass 1: v = r*(k/(rms+EPS))
    float kd1f = kf * __builtin_amdgcn_rcpf(rmsf + EPSF);
    f32x2 c1[4];
    #pragma unroll
    for (int i = 0; i < 4; ++i) {
      c1[i].x = qcent(r[i].x * kd1f);
      c1[i].y = qcent(r[i].y * kd1f);
    }

    // gamma refine (packed accumulate)
    f32x2 nmv = r[0] * c1[0];
    f32x2 dnv = c1[0] * c1[0];
    #pragma unroll
    for (int i = 1; i < 4; ++i) {
      nmv = __builtin_elementwise_fma(r[i],  c1[i], nmv);
      dnv = __builtin_elementwise_fma(c1[i], c1[i], dnv);
    }
    float gamma1 = redsum16f(nmv.x + nmv.y) * kf *
                   __builtin_amdgcn_rcpf(redsum16f(dnv.x + dnv.y) + EPSF);

    // pass 2
    float kd2f = kf * __builtin_amdgcn_rcpf(gamma1 + EPSF);
    f32x2 c2[4];
    #pragma unroll
    for (int i = 0; i < 4; ++i) {
      c2[i].x = qcent(r[i].x * kd2f);
      c2[i].y = qcent(r[i].y * kd2f);
    }

    // reconstruct; fold gamma*FSC*norms into one pre-FWHT scalar (linearity)
    float g2s = (spiky ? rmsf : gamma1) * fscf * nf;
    const f32x2 g2v = { g2s, g2s };
    f32x2 y[4];
    #pragma unroll
    for (int i = 0; i < 4; ++i) y[i] = (spiky ? c1[i] : c2[i]) * g2v;
    fwht128v(y, sAv, sBv, sCv, sDv);

    #pragma unroll
    for (int i = 0; i < 4; ++i) y[i] = y[i] * sg[i];
    float4 oa, ob;
    oa.x = y[0].x; oa.y = y[0].y; oa.z = y[1].x; oa.w = y[1].y;
    ob.x = y[2].x; ob.y = y[2].y; ob.z = y[3].x; ob.w = y[3].y;
    float* op = out + 4 * t * 128 + base_off;
    *reinterpret_cast<float4*>(op)     = oa;
    *reinterpret_cast<float4*>(op + 4) = ob;

    if (!more) break;
    t = tn; xa = na; xb = nb;
  }
}

extern "C" void kernel_launch(void* const* d_in, const int* in_sizes, int n_in,
                              void* d_out, int out_size, void* d_ws, size_t ws_size,
                              hipStream_t stream) {
  const float* x     = (const float*)d_in[0];
  const float* signs = (const float*)d_in[1];
  // d_in[2] = wht (unused: Sylvester Hadamard applied as in-register FWHT)
  const float* bnd   = (const float*)d_in[3];
  const float* ctr   = (const float*)d_in[4];
  float* out = (float*)d_out;

  int nrows  = out_size / 128;
  int nquads = nrows / 4;                    // 4 rows per wave
  int blocks = (nquads + 3) / 4;             // 4 waves per block
  if (blocks > 2048) blocks = 2048;
  hipLaunchKernelGGL(tq_kernel, dim3(blocks), dim3(256), 0, stream,
                     x, signs, bnd, ctr, out, nquads);
}